// Round 8
// baseline (568.663 us; speedup 1.0000x reference)
//
#include <hip/hip_runtime.h>
#include <hip/hip_bf16.h>

typedef float        fx4 __attribute__((ext_vector_type(4)));
typedef float        fx2 __attribute__((ext_vector_type(2)));
typedef unsigned int ux4 __attribute__((ext_vector_type(4)));

#define NC   8192   // N*C
#define EPSF 1e-5f

// ---------------------------------------------------------------------------
// Kernel 1: phi (pre-scaled by alpha) -> bf16 in ws, SWIZZLED for the fused
// kernel's access pattern. Logical element (k, j), k=0..8191, j=0..23
// (j<4: pre col j, j<8: post col j-4, j>=8: res col j-8, row-major [4][4]).
// k = 2048*d + 4*tid + u  (d=0..3, u=0..3, tid=0..511);  j = 8*t3 + e2.
// Stored flat u16 index = (((d*4+u)*3 + t3)*512 + tid)*8 + e2
// -> in fused_k, lane reads ux4 at [(s*3+t3)*512 + tid]: 16B/lane contiguous.
// ---------------------------------------------------------------------------
__global__ __launch_bounds__(256) void cvt_phi_k(
    const float* __restrict__ phi_pre,
    const float* __restrict__ phi_post,
    const float* __restrict__ phi_res,
    const float* __restrict__ a_pre,
    const float* __restrict__ a_post,
    const float* __restrict__ a_res,
    unsigned short* __restrict__ wphi)
{
    int idx = blockIdx.x * 256 + threadIdx.x;   // 0 .. 196607
    int e2  = idx & 7;
    int q1  = idx >> 3;          // 0..24575
    int tid = q1 & 511;
    int q2  = q1 >> 9;           // 0..47
    int t3  = q2 % 3;
    int du  = q2 / 3;            // 0..15  = 4d+u
    int d   = du >> 2, u = du & 3;
    int k   = 2048 * d + 4 * tid + u;
    int j   = 8 * t3 + e2;
    float v;
    if (j < 4)      v = phi_pre [k * 4 + j]        * a_pre[0];
    else if (j < 8) v = phi_post[k * 4 + (j - 4)]  * a_post[0];
    else            v = phi_res [k * 16 + (j - 8)] * a_res[0];
    __hip_bfloat16 b = __float2bfloat16(v);
    wphi[idx] = *reinterpret_cast<unsigned short*>(&b);
}

// ---------------------------------------------------------------------------
// Kernel 2: fused connector. Block = 512 thr = 2 tokens; 4096 blocks.
// Thread owns x[t][i][c] for c = 4*tid+u (u=0..3), ALL i=0..3  ->
//   k = 2048*i + 4*tid + u. x: 8 nontemporal float4 loads, never in LDS.
// phi read straight from L2, fully coalesced (swizzled layout); MAC written
// as fx2 vector math so the compiler can emit v_pk_fma_f32 (dual-issue).
// NO barriers until the reductions. Occupancy: VGPR-limited 2 blocks/CU.
// ---------------------------------------------------------------------------
__global__ __launch_bounds__(512, 4) void fused_k(
    const float* __restrict__ x,
    const unsigned short* __restrict__ wphi,   // swizzled, 384 KB
    const float* __restrict__ b_pre,
    const float* __restrict__ b_post,
    const float* __restrict__ b_res,
    const float* __restrict__ norm_scale,
    float* __restrict__ out)
{
    __shared__ fx2  red2[256][27];   // 55296 B (stride 54 f32 -> 2-way, free)
    __shared__ float sums2[8][52];
    __shared__ float sums[52];
    __shared__ float tilde_s[2][24];
    __shared__ float M_s[2][16];
    __shared__ float Hpre_s[2][4];
    __shared__ float Hpost_s[2][4];
    __shared__ float iagg_s[2];
    __shared__ fx2  ared[128];

    const int tid  = threadIdx.x;      // 0..511
    const int lane = tid & 63;
    const int wv   = tid >> 6;         // 0..7
    const long tok0 = (long)blockIdx.x * 2;

    // ---- x: 8 x float4 NT loads (k = 2048d + 4tid + u) ----
    const fx4* xv0 = (const fx4*)(x + tok0 * NC) + tid;
    const fx4* xv1 = xv0 + (NC / 4);
    fx4 xr0[4], xr1[4];
#pragma unroll
    for (int d = 0; d < 4; ++d) {
        xr0[d] = __builtin_nontemporal_load(xv0 + d * 512);
        xr1[d] = __builtin_nontemporal_load(xv1 + d * 512);
    }

    // ---- matvec: acc[p] covers cols (2p, 2p+1); fx2 math -> v_pk_fma_f32 ----
    fx2 acc0[12], acc1[12];
#pragma unroll
    for (int p = 0; p < 12; ++p) { acc0[p] = (fx2)0.f; acc1[p] = (fx2)0.f; }

    const ux4* wv4 = (const ux4*)wphi;
#pragma unroll
    for (int s = 0; s < 16; ++s) {          // s = 4d + u
        const int d = s >> 2, u = s & 3;
        fx2 xa2; xa2[0] = xr0[d][u]; xa2[1] = xr0[d][u];
        fx2 xb2; xb2[0] = xr1[d][u]; xb2[1] = xr1[d][u];
#pragma unroll
        for (int t3 = 0; t3 < 3; ++t3) {
            ux4 ww = wv4[(s * 3 + t3) * 512 + tid];   // coalesced 16B/lane
#pragma unroll
            for (int e = 0; e < 4; ++e) {
                unsigned q = ww[e];
                fx2 lohi;
                lohi[0] = __uint_as_float(q << 16);          // col 2p
                lohi[1] = __uint_as_float(q & 0xffff0000u);  // col 2p+1
                const int p = t3 * 4 + e;
                acc0[p] += lohi * xa2;
                acc1[p] += lohi * xb2;
            }
        }
    }

    // ---- ssq(x) per token ----
    float ssq0 = 0.f, ssq1 = 0.f;
#pragma unroll
    for (int d = 0; d < 4; ++d)
#pragma unroll
        for (int u = 0; u < 4; ++u) {
            ssq0 = fmaf(xr0[d][u], xr0[d][u], ssq0);
            ssq1 = fmaf(xr1[d][u], xr1[d][u], ssq1);
        }

    // ---- reduce: 1 shuffle level -> lanes 0..31 -> LDS tree ----
    ssq0 += __shfl_down(ssq0, 32);
    ssq1 += __shfl_down(ssq1, 32);
#pragma unroll
    for (int p = 0; p < 12; ++p) {
        acc0[p][0] += __shfl_down(acc0[p][0], 32);
        acc0[p][1] += __shfl_down(acc0[p][1], 32);
        acc1[p][0] += __shfl_down(acc1[p][0], 32);
        acc1[p][1] += __shfl_down(acc1[p][1], 32);
    }
    if (lane < 32) {
        const int row = wv * 32 + lane;
#pragma unroll
        for (int p = 0; p < 12; ++p) {
            red2[row][p]      = acc0[p];   // f32 cols 0..23  = tok0 dots
            red2[row][12 + p] = acc1[p];   // f32 cols 24..47 = tok1 dots
        }
        fx2 sp; sp[0] = ssq0; sp[1] = ssq1;
        red2[row][24] = sp;                // f32 cols 48,49 = ssq
    }
    __syncthreads();

    // stage B1: 8 waves x 26 fx2-cols, each sums 32 rows (ds_read_b64,
    // lanes at consecutive 8B -> conflict-free)
    {
        const int g = wv, c2 = lane;
        if (c2 < 26) {
            const fx2* base = &red2[g * 32][0] + c2;
            fx2 s = (fx2)0.f;
#pragma unroll
            for (int r = 0; r < 32; ++r) s += base[r * 27];
            sums2[g][2 * c2]     = s[0];
            sums2[g][2 * c2 + 1] = s[1];
        }
    }
    __syncthreads();
    if (tid < 52) {
        float s = 0.f;
#pragma unroll
        for (int g = 0; g < 8; ++g) s += sums2[g][tid];
        sums[tid] = s;
    }
    __syncthreads();

    // ---- tilde[t][j] = dot * inv_rms + bias ----
    if (tid < 48) {
        const int t = tid >= 24;
        const int j = tid - 24 * t;
        float irms = 1.0f / sqrtf(sums[48 + t] * (1.0f / 8192.0f) + EPSF);
        float bias = (j < 4) ? b_pre[j] : (j < 8) ? b_post[j - 4] : b_res[j - 8];
        tilde_s[t][j] = sums[tid] * irms + bias;
    }
    __syncthreads();

    // ---- sinkhorn (lanes 0..31: 2 tok x 16 cells) || gates (wave 1) ----
    // self-normalizing iteration -> fast v_rcp_f32 is numerically safe and
    // cuts the 20x serial divide chains to ~1 op each
    if (tid < 32) {
        const int t = tid >> 4;
        float m = expf(tilde_s[t][8 + (tid & 15)]);   // cell l = 4i+jj
        for (int it = 0; it < 20; ++it) {
            float r1 = m + __shfl_xor(m, 1);          // row sum (axis=-1)
            float rs = r1 + __shfl_xor(r1, 2);
            m = m * __builtin_amdgcn_rcpf(rs + EPSF);
            float c1 = m + __shfl_xor(m, 4);          // col sum (axis=-2)
            float cs = c1 + __shfl_xor(c1, 8);
            m = m * __builtin_amdgcn_rcpf(cs + EPSF);
        }
        M_s[t][tid & 15] = m;
    } else if (tid >= 64 && tid < 80) {
        const int u = tid - 64, t = u >> 3, q = u & 7;
        if (q < 4) Hpre_s [t][q]     = 1.0f / (1.0f + expf(-tilde_s[t][q]));
        else       Hpost_s[t][q - 4] = 2.0f / (1.0f + expf(-tilde_s[t][q]));
    }
    __syncthreads();

    // ---- x_agg (same c for all i -> thread-local) + its ssq ----
    fx4 xaA = Hpre_s[0][0] * xr0[0] + Hpre_s[0][1] * xr0[1]
            + Hpre_s[0][2] * xr0[2] + Hpre_s[0][3] * xr0[3];
    fx4 xaB = Hpre_s[1][0] * xr1[0] + Hpre_s[1][1] * xr1[1]
            + Hpre_s[1][2] * xr1[2] + Hpre_s[1][3] * xr1[3];
    float sa0 = xaA[0]*xaA[0] + xaA[1]*xaA[1] + xaA[2]*xaA[2] + xaA[3]*xaA[3];
    float sa1 = xaB[0]*xaB[0] + xaB[1]*xaB[1] + xaB[2]*xaB[2] + xaB[3]*xaB[3];
    sa0 += __shfl_down(sa0, 32);  sa1 += __shfl_down(sa1, 32);
    sa0 += __shfl_down(sa0, 16);  sa1 += __shfl_down(sa1, 16);
    if (lane < 16) {
        fx2 sp; sp[0] = sa0; sp[1] = sa1;
        ared[wv * 16 + lane] = sp;
    }
    __syncthreads();
    // 64-lane parallel tail (each lane sums 2 entries, then butterfly)
    if (tid < 64) {
        fx2 v = ared[tid] + ared[tid + 64];
#pragma unroll
        for (int off = 32; off >= 1; off >>= 1) {
            v[0] += __shfl_down(v[0], off);
            v[1] += __shfl_down(v[1], off);
        }
        if (tid == 0) {
            iagg_s[0] = 1.0f / sqrtf(v[0] * (1.0f / 2048.0f) + EPSF);
            iagg_s[1] = 1.0f / sqrtf(v[1] * (1.0f / 2048.0f) + EPSF);
        }
    }
    __syncthreads();

    // ---- epilogue: out[i][c] = sum_j M[i][j]*x[j][c] + Hpost[i]*xn[c] ----
    const float ia0 = iagg_s[0], ia1 = iagg_s[1];
    fx4 ns = *(const fx4*)(norm_scale + 4 * tid);
    fx4 xn0 = xaA * ia0 * ns;
    fx4 xn1 = xaB * ia1 * ns;
    float* o0 = out + tok0 * NC + 4 * tid;
#pragma unroll
    for (int i = 0; i < 4; ++i) {
        fx4 oa = Hpost_s[0][i] * xn0
               + M_s[0][i*4+0] * xr0[0] + M_s[0][i*4+1] * xr0[1]
               + M_s[0][i*4+2] * xr0[2] + M_s[0][i*4+3] * xr0[3];
        __builtin_nontemporal_store(oa, (fx4*)(o0 + i * 2048));
        fx4 ob = Hpost_s[1][i] * xn1
               + M_s[1][i*4+0] * xr1[0] + M_s[1][i*4+1] * xr1[1]
               + M_s[1][i*4+2] * xr1[2] + M_s[1][i*4+3] * xr1[3];
        __builtin_nontemporal_store(ob, (fx4*)(o0 + NC + i * 2048));
    }
}

extern "C" void kernel_launch(void* const* d_in, const int* in_sizes, int n_in,
                              void* d_out, int out_size, void* d_ws, size_t ws_size,
                              hipStream_t stream) {
    const float* x        = (const float*)d_in[0];
    const float* phi_pre  = (const float*)d_in[1];
    const float* phi_post = (const float*)d_in[2];
    const float* phi_res  = (const float*)d_in[3];
    const float* b_pre    = (const float*)d_in[4];
    const float* b_post   = (const float*)d_in[5];
    const float* b_res    = (const float*)d_in[6];
    const float* a_pre    = (const float*)d_in[7];
    const float* a_post   = (const float*)d_in[8];
    const float* a_res    = (const float*)d_in[9];
    const float* nscale   = (const float*)d_in[10];
    float* outp = (float*)d_out;
    unsigned short* wphi = (unsigned short*)d_ws;   // 196608 bf16 = 384 KB

    cvt_phi_k<<<768, 256, 0, stream>>>(phi_pre, phi_post, phi_res,
                                       a_pre, a_post, a_res, wphi);

    int tokens = in_sizes[0] / NC;      // 8192
    int blocks = tokens / 2;            // 4096
    fused_k<<<blocks, 512, 0, stream>>>(x, wphi, b_pre, b_post, b_res,
                                        nscale, outp);
}